// Round 9
// baseline (117.132 us; speedup 1.0000x reference)
//
#include <hip/hip_runtime.h>
#include <hip/hip_bf16.h>
#include <math.h>

#define CIN   64
#define COUT  32
#define K1V   17
#define HV    4
#define RPB   64          // rows per proj block
#define XPAD  68          // LDS x-row stride (floats)
#define NPB   8           // nodes per gcn block

typedef float v4f __attribute__((ext_vector_type(4)));

// Kernel T: precompute per-(n,k) head weights w[4], safe gather idx, and
// per-(n,h) dist_agg. Runs once (amortizes the 24x redundant rebuild).
__global__ __launch_bounds__(256) void table_kernel(
    const float* __restrict__ dist, const int* __restrict__ nn,
    float* __restrict__ wtab,   // (N*K1, 4)
    int*   __restrict__ itab,   // (N*K1)
    float* __restrict__ dagtab, // (N, 4)
    int N) {
  __shared__ float wl[NPB][K1V][HV];
  __shared__ float dl[NPB][K1V];
  int tid = threadIdx.x;
  int n0  = blockIdx.x * NPB;

  if (tid < NPB * K1V) {
    int l = tid / K1V, k = tid % K1V;
    int n_ = n0 + l;
    float w0 = 0, w1 = 0, w2 = 0, w3 = 0, dc = 0;
    if (n_ < N) {
      long  gi = (long)n_ * K1V + k;
      float d  = dist[gi];
      int idx = nn[gi];
      float d2 = d * d;
      w0 = __expf(-d2 * 0.25f);
      w1 = __expf(-d2 * 0.50f);
      w2 = __expf(-d2 * 0.75f);
      w3 = __expf(-d2);
      if (idx == -1) { w0 = w1 = w2 = w3 = 0.0f; }
      if (w0 < 1e-5f) w0 = 0.0f;
      if (w1 < 1e-5f) w1 = 0.0f;
      if (w2 < 1e-5f) w2 = 0.0f;
      if (w3 < 1e-5f) w3 = 0.0f;
      dc = isinf(d) ? 0.0f : d;
      if (idx < 0 || idx >= N) idx = 0;   // its w==0; safe address
      v4f w4 = { w0, w1, w2, w3 };
      *(v4f*)&wtab[gi * 4] = w4;
      itab[gi] = idx;
    }
    wl[l][k][0] = w0; wl[l][k][1] = w1; wl[l][k][2] = w2; wl[l][k][3] = w3;
    dl[l][k] = dc;
  }
  __syncthreads();

  if (tid < NPB * HV) {
    int l = tid >> 2, h = tid & 3;
    int n_ = n0 + l;
    if (n_ < N) {
      float s = 0.0f;
#pragma unroll
      for (int k = 0; k < K1V; ++k) s = fmaf(wl[l][k][h], dl[l][k], s);
      dagtab[(long)n_ * HV + h] = s;
    }
  }
}

// Kernel A (R5 structure, best measured): xp[r,o] = sum_i x[r,i]*W[o,i]+b[o]
// 64-row x tile in LDS; wave w owns outs [8w,8w+8) -> W/b wave-uniform
// (readfirstlane) -> scalar s_loads; x fragments via ds_read_b128.
__global__ __launch_bounds__(256) void proj_kernel(
    const float* __restrict__ x, const float* __restrict__ W,
    const float* __restrict__ b, float* __restrict__ xp, long nrows) {
  __shared__ float Xl[RPB * XPAD];   // 17408 B
  int tid = threadIdx.x;
  long r0 = (long)blockIdx.x * RPB;

  const v4f* xg = (const v4f*)(x + r0 * CIN);
#pragma unroll
  for (int s = 0; s < 4; ++s) {
    int fi  = tid + s * 256;
    int row = fi >> 4;
    int col = (fi & 15) << 2;
    *(v4f*)&Xl[row * XPAD + col] = xg[fi];
  }
  __syncthreads();

  int wv   = __builtin_amdgcn_readfirstlane(tid >> 6);  // wave id (SGPR)
  int lane = tid & 63;
  long r = r0 + lane;
  if (r >= nrows) return;

  const float* Wb = W + wv * 8 * CIN;   // uniform base
  float acc[8];
#pragma unroll
  for (int oo = 0; oo < 8; ++oo) acc[oo] = b[wv * 8 + oo];

#pragma unroll
  for (int j = 0; j < CIN / 4; ++j) {
    v4f xv = *(const v4f*)&Xl[lane * XPAD + j * 4];
#pragma unroll
    for (int oo = 0; oo < 8; ++oo) {
      v4f w4 = *(const v4f*)(Wb + oo * CIN + j * 4);  // s_load_dwordx4
      acc[oo] = fmaf(xv.x, w4.x,
                fmaf(xv.y, w4.y,
                fmaf(xv.z, w4.z,
                fmaf(xv.w, w4.w, acc[oo]))));
    }
  }

  float* op = xp + r * COUT + wv * 8;
  v4f lo = { acc[0], acc[1], acc[2], acc[3] };
  v4f hi = { acc[4], acc[5], acc[6], acc[7] };
  *(v4f*)op       = lo;
  *(v4f*)(op + 4) = hi;
}

// Kernel C: grid (node_groups, BT), x fastest (co-resident blocks share one
// 1.28MB slice -> L2-hot). Per block: stage table, then cooperatively stage
// the 136 gathered rows (8 nodes x 17 nbrs x 128B) into LDS with float4
// loads (1088 VMEM insts vs 4352 scalar gathers), then each thread
// (node, head, chquad) reads ds_read_b128 (conflict-free: h-dups broadcast,
// 2-way node alias free) and does 17x4 FMA -> one b128 nt store.
__global__ __launch_bounds__(256) void gcn_kernel(
    const float* __restrict__ xp,     // (BT, N, 32)
    const float* __restrict__ wtab,   // (N*K1, 4)
    const int*   __restrict__ itab,   // (N*K1)
    const float* __restrict__ dagtab, // (N, 4)
    float* __restrict__ out,          // (BT, N, H, 32)
    int N) {
  __shared__ float wl[NPB * K1V][HV];  // 2176 B
  __shared__ int   nlf[NPB * K1V];     // 544 B
  __shared__ float dagl[NPB][HV];      // 128 B
  __shared__ float Gl[NPB * K1V * COUT];  // 17408 B gathered rows

  int tid = threadIdx.x;
  int bt  = blockIdx.y;
  int n0  = blockIdx.x * NPB;

  // Phase 1: stage table
  if (tid < NPB * K1V) {
    long gi = (long)n0 * K1V + tid;
    v4f w4 = { 0, 0, 0, 0 };
    int idx = 0;
    if (n0 + tid / K1V < N) {
      w4  = *(const v4f*)&wtab[gi * 4];
      idx = itab[gi];
    }
    *(v4f*)&wl[tid][0] = w4;
    nlf[tid] = idx;
  } else if (tid < NPB * K1V + NPB * HV) {
    int t = tid - NPB * K1V;
    int l = t >> 2, h = t & 3;
    dagl[l][h] = (n0 + l < N) ? dagtab[(long)(n0 + l) * HV + h] : 0.0f;
  }
  __syncthreads();

  // Phase 2: stage 136 rows x 32 floats as float4 chunks (1088 chunks)
  const float* base = xp + (size_t)bt * N * COUT;
  v4f* Gl4 = (v4f*)Gl;
#pragma unroll
  for (int it = 0; it < 5; ++it) {
    int ci = tid + it * 256;
    if (ci < NPB * K1V * 8) {
      int row = ci >> 3;
      int q   = ci & 7;
      v4f v = *(const v4f*)(base + (size_t)nlf[row] * COUT + q * 4);
      Gl4[ci] = v;
    }
  }
  __syncthreads();

  int cq = tid & 7;           // channel quad
  int h  = (tid >> 3) & 3;    // head
  int ln = tid >> 5;          // local node
  int n  = n0 + ln;
  if (n >= N) return;

  float4 dummy;
  v4f a;
  {
    float dag = dagl[ln][h];
    a.x = dag; a.y = dag; a.z = dag; a.w = dag;
  }
#pragma unroll
  for (int k = 0; k < K1V; ++k) {
    int row = ln * K1V + k;
    v4f v  = Gl4[row * 8 + cq];       // ds_read_b128, conflict-free
    float w = wl[row][h];             // broadcast within 8-lane groups
    a.x = fmaf(w, v.x, a.x);
    a.y = fmaf(w, v.y, a.y);
    a.z = fmaf(w, v.z, a.z);
    a.w = fmaf(w, v.w, a.w);
  }

  v4f* ob = (v4f*)(out + (((size_t)bt * N + n) * HV + h) * COUT + cq * 4);
  __builtin_nontemporal_store(a, ob);
}

extern "C" void kernel_launch(void* const* d_in, const int* in_sizes, int n_in,
                              void* d_out, int out_size, void* d_ws, size_t ws_size,
                              hipStream_t stream) {
  const float* x    = (const float*)d_in[0];
  const float* W    = (const float*)d_in[1];
  const float* b    = (const float*)d_in[2];
  const float* dist = (const float*)d_in[3];
  const int*   nn   = (const int*)d_in[4];
  float* out = (float*)d_out;

  int  N  = in_sizes[4] / K1V;                 // 10000
  long M  = (long)in_sizes[0] / CIN;           // BT * N = 240000
  int  BT = (int)(M / N);                      // 24

  // workspace layout (256B-aligned): xp | wtab | itab | dagtab  (~35 MB)
  char* ws = (char*)d_ws;
  size_t off = 0;
  float* xp = (float*)(ws + off);
  off += (size_t)M * COUT * sizeof(float);      off = (off + 255) & ~(size_t)255;
  float* wtab = (float*)(ws + off);
  off += (size_t)N * K1V * 4 * sizeof(float);   off = (off + 255) & ~(size_t)255;
  int* itab = (int*)(ws + off);
  off += (size_t)N * K1V * sizeof(int);         off = (off + 255) & ~(size_t)255;
  float* dagtab = (float*)(ws + off);

  int ngroups = (N + NPB - 1) / NPB;            // 1250

  table_kernel<<<ngroups, 256, 0, stream>>>(dist, nn, wtab, itab, dagtab, N);
  proj_kernel<<<(int)((M + RPB - 1) / RPB), 256, 0, stream>>>(x, W, b, xp, M);

  dim3 grid(ngroups, BT);                       // 1250 x 24, x fastest
  gcn_kernel<<<grid, 256, 0, stream>>>(xp, wtab, itab, dagtab, out, N);
}

// Round 10
// 94.052 us; speedup vs baseline: 1.2454x; 1.2454x over previous
//
#include <hip/hip_runtime.h>
#include <hip/hip_bf16.h>
#include <math.h>

#define CIN   64
#define COUT  32
#define K1V   17
#define HV    4
#define RPB   64          // rows per proj block
#define XPAD  68          // LDS x-row stride (floats)
#define NXCD  8

typedef float v4f __attribute__((ext_vector_type(4)));

// Kernel A (R5 structure, best measured): xp[r,o] = sum_i x[r,i]*W[o,i]+b[o]
// 64-row x tile in LDS; wave w owns outs [8w,8w+8) -> W/b wave-uniform
// (readfirstlane) -> scalar s_loads; x fragments via ds_read_b128.
__global__ __launch_bounds__(256) void proj_kernel(
    const float* __restrict__ x, const float* __restrict__ W,
    const float* __restrict__ b, float* __restrict__ xp, long nrows) {
  __shared__ float Xl[RPB * XPAD];   // 17408 B
  int tid = threadIdx.x;
  long r0 = (long)blockIdx.x * RPB;

  const v4f* xg = (const v4f*)(x + r0 * CIN);
#pragma unroll
  for (int s = 0; s < 4; ++s) {
    int fi  = tid + s * 256;
    int row = fi >> 4;
    int col = (fi & 15) << 2;
    *(v4f*)&Xl[row * XPAD + col] = xg[fi];
  }
  __syncthreads();

  int wv   = __builtin_amdgcn_readfirstlane(tid >> 6);  // wave id (SGPR)
  int lane = tid & 63;
  long r = r0 + lane;
  if (r >= nrows) return;

  const float* Wb = W + wv * 8 * CIN;   // uniform base
  float acc[8];
#pragma unroll
  for (int oo = 0; oo < 8; ++oo) acc[oo] = b[wv * 8 + oo];

#pragma unroll
  for (int j = 0; j < CIN / 4; ++j) {
    v4f xv = *(const v4f*)&Xl[lane * XPAD + j * 4];
#pragma unroll
    for (int oo = 0; oo < 8; ++oo) {
      v4f w4 = *(const v4f*)(Wb + oo * CIN + j * 4);  // s_load_dwordx4
      acc[oo] = fmaf(xv.x, w4.x,
                fmaf(xv.y, w4.y,
                fmaf(xv.z, w4.z,
                fmaf(xv.w, w4.w, acc[oo]))));
    }
  }

  float* op = xp + r * COUT + wv * 8;
  v4f lo = { acc[0], acc[1], acc[2], acc[3] };
  v4f hi = { acc[4], acc[5], acc[6], acc[7] };
  *(v4f*)op       = lo;
  *(v4f*)(op + 4) = hi;
}

// Kernel C (R5 structure + XCD confinement): 1-D grid, 30000 blocks.
// Decode: xcd = bid % 8 owns bt in [xcd*3, xcd*3+3) -> each 1.28MB bt-slice
// is gathered by exactly ONE XCD's L2 (neighbors are random within slice, so
// cross-XCD spreading forced 8x slice refetch = the 149MB FETCH).
// Block = 8 nodes x 32 ch; thread owns all 4 heads of one (node, ch);
// 17 scalar coalesced gathers (half-wave = one 128B line); nt stores.
__global__ __launch_bounds__(256) void gcn_kernel(
    const float* __restrict__ xp,    // (BT, N, 32)
    const float* __restrict__ dist,  // (N, K1)
    const int*   __restrict__ nn,    // (N, K1)
    float* __restrict__ out,         // (BT, N, H, 32)
    int BT, int N, int ngroups, int btPerXcd) {
  __shared__ float wl[8][K1V][HV];
  __shared__ float dl[8][K1V];
  __shared__ int   nl[8][K1V];
  __shared__ float dagl[8][HV];

  int tid = threadIdx.x;
  int bid = blockIdx.x;
  // XCD-confinement decode (round-robin dispatch assumption: xcd = bid % 8)
  int xcd = bid & (NXCD - 1);
  int j   = bid >> 3;              // 0 .. ngroups*btPerXcd-1
  int bt  = xcd * btPerXcd + j / ngroups;
  int n0  = (j % ngroups) * 8;
  if (bt >= BT) return;

  if (tid < 8 * K1V) {        // 136 builder threads
    int l = tid / K1V, k = tid % K1V;
    int n_ = n0 + l;
    float w0 = 0, w1 = 0, w2 = 0, w3 = 0, dc = 0;
    int idx = 0;
    if (n_ < N) {
      float d = dist[(long)n_ * K1V + k];
      idx = nn[(long)n_ * K1V + k];
      float d2 = d * d;
      w0 = __expf(-d2 * 0.25f);
      w1 = __expf(-d2 * 0.50f);
      w2 = __expf(-d2 * 0.75f);
      w3 = __expf(-d2);
      if (idx == -1) { w0 = w1 = w2 = w3 = 0.0f; }
      if (w0 < 1e-5f) w0 = 0.0f;
      if (w1 < 1e-5f) w1 = 0.0f;
      if (w2 < 1e-5f) w2 = 0.0f;
      if (w3 < 1e-5f) w3 = 0.0f;
      dc = isinf(d) ? 0.0f : d;
      if (idx < 0 || idx >= N) idx = 0;   // its w==0; safe address
    }
    wl[l][k][0] = w0; wl[l][k][1] = w1; wl[l][k][2] = w2; wl[l][k][3] = w3;
    dl[l][k] = dc; nl[l][k] = idx;
  }
  __syncthreads();

  if (tid < 8 * HV) {         // fold dist_agg once per (node, head)
    int l = tid >> 2, h = tid & 3;
    float s = 0.0f;
#pragma unroll
    for (int k = 0; k < K1V; ++k) s = fmaf(wl[l][k][h], dl[l][k], s);
    dagl[l][h] = s;
  }
  __syncthreads();

  int ln = tid >> 5;          // local node
  int c  = tid & 31;          // channel
  int n  = n0 + ln;
  if (n >= N) return;

  const float* base = xp + (size_t)bt * N * COUT + c;
  float a0 = dagl[ln][0], a1 = dagl[ln][1], a2 = dagl[ln][2], a3 = dagl[ln][3];

#pragma unroll
  for (int k = 0; k < K1V; ++k) {
    int   idx = nl[ln][k];
    float v   = base[(size_t)idx * COUT];
    v4f w4 = *(const v4f*)&wl[ln][k][0];
    a0 = fmaf(w4.x, v, a0);
    a1 = fmaf(w4.y, v, a1);
    a2 = fmaf(w4.z, v, a2);
    a3 = fmaf(w4.w, v, a3);
  }

  float* ob = out + (((size_t)bt * N + n) * HV) * COUT + c;
  __builtin_nontemporal_store(a0, ob);
  __builtin_nontemporal_store(a1, ob + COUT);
  __builtin_nontemporal_store(a2, ob + 2 * COUT);
  __builtin_nontemporal_store(a3, ob + 3 * COUT);
}

extern "C" void kernel_launch(void* const* d_in, const int* in_sizes, int n_in,
                              void* d_out, int out_size, void* d_ws, size_t ws_size,
                              hipStream_t stream) {
  const float* x    = (const float*)d_in[0];
  const float* W    = (const float*)d_in[1];
  const float* b    = (const float*)d_in[2];
  const float* dist = (const float*)d_in[3];
  const int*   nn   = (const int*)d_in[4];
  float* out = (float*)d_out;
  float* xp  = (float*)d_ws;   // (BT, N, 32) fp32 = 30.72 MB

  int  N  = in_sizes[4] / K1V;                 // 10000
  long M  = (long)in_sizes[0] / CIN;           // BT * N = 240000
  int  BT = (int)(M / N);                      // 24

  proj_kernel<<<(int)((M + RPB - 1) / RPB), 256, 0, stream>>>(x, W, b, xp, M);

  int ngroups  = (N + 7) / 8;                  // 1250
  int btPerXcd = (BT + NXCD - 1) / NXCD;       // 3
  int nblocks  = ngroups * btPerXcd * NXCD;    // 30000
  gcn_kernel<<<nblocks, 256, 0, stream>>>(xp, dist, nn, out, BT, N, ngroups, btPerXcd);
}

// Round 11
// 89.393 us; speedup vs baseline: 1.3103x; 1.0521x over previous
//
#include <hip/hip_runtime.h>
#include <hip/hip_bf16.h>
#include <math.h>

#define CIN   64
#define COUT  32
#define K1V   17
#define HV    4
#define RPB   64          // rows per proj block
#define XPAD  68          // LDS x-row stride (floats)

typedef float v4f __attribute__((ext_vector_type(4)));

// Kernel A: xp[r,o] = sum_i x[r,i]*W[o,i] + b[o]
// 64-row x tile AND W/b staged in LDS. Wave w owns outs [8w,8w+8).
// All inner-loop loads are ds_read (homogeneous lgkmcnt -> partial waits,
// pipelined), W reads are wave-uniform -> broadcast, conflict-free.
__global__ __launch_bounds__(256) void proj_kernel(
    const float* __restrict__ x, const float* __restrict__ W,
    const float* __restrict__ b, float* __restrict__ xp, long nrows) {
  __shared__ float Xl[RPB * XPAD];   // 17408 B
  __shared__ float Wl[COUT * CIN];   // 8192 B
  __shared__ float bl[COUT];
  int tid = threadIdx.x;
  long r0 = (long)blockIdx.x * RPB;

  {  // stage W (512 float4) + b
    const v4f* wg = (const v4f*)W;
    v4f* ws = (v4f*)Wl;
    ws[tid]       = wg[tid];
    ws[tid + 256] = wg[tid + 256];
    if (tid < COUT) bl[tid] = b[tid];
  }
  {  // stage x tile (1024 float4)
    const v4f* xg = (const v4f*)(x + r0 * CIN);
#pragma unroll
    for (int s = 0; s < 4; ++s) {
      int fi  = tid + s * 256;
      int row = fi >> 4;
      int col = (fi & 15) << 2;
      *(v4f*)&Xl[row * XPAD + col] = xg[fi];
    }
  }
  __syncthreads();

  int wv   = __builtin_amdgcn_readfirstlane(tid >> 6);  // wave id (SGPR)
  int lane = tid & 63;
  long r = r0 + lane;
  if (r >= nrows) return;

  float acc[8];
#pragma unroll
  for (int oo = 0; oo < 8; ++oo) acc[oo] = bl[wv * 8 + oo];

#pragma unroll
  for (int j = 0; j < CIN / 4; ++j) {
    v4f xv = *(const v4f*)&Xl[lane * XPAD + j * 4];
#pragma unroll
    for (int oo = 0; oo < 8; ++oo) {
      v4f w4 = *(const v4f*)&Wl[(wv * 8 + oo) * CIN + j * 4];  // uniform -> LDS broadcast
      acc[oo] = fmaf(xv.x, w4.x,
                fmaf(xv.y, w4.y,
                fmaf(xv.z, w4.z,
                fmaf(xv.w, w4.w, acc[oo]))));
    }
  }

  float* op = xp + r * COUT + wv * 8;
  v4f lo = { acc[0], acc[1], acc[2], acc[3] };
  v4f hi = { acc[4], acc[5], acc[6], acc[7] };
  *(v4f*)op       = lo;
  *(v4f*)(op + 4) = hi;
}

// Kernel C (exact 86.9us-best structure): grid (node_groups, BT), x fastest
// -> co-resident blocks share one 1.28MB slice (L2-hot). Block = 8 nodes x
// 32 ch; thread owns all 4 heads of one (node, ch); 17 scalar coalesced
// gathers; nt stores.
__global__ __launch_bounds__(256) void gcn_kernel(
    const float* __restrict__ xp,    // (BT, N, 32)
    const float* __restrict__ dist,  // (N, K1)
    const int*   __restrict__ nn,    // (N, K1)
    float* __restrict__ out,         // (BT, N, H, 32)
    int N) {
  __shared__ float wl[8][K1V][HV];
  __shared__ float dl[8][K1V];
  __shared__ int   nl[8][K1V];
  __shared__ float dagl[8][HV];

  int tid = threadIdx.x;
  int bt  = blockIdx.y;
  int n0  = blockIdx.x * 8;

  if (tid < 8 * K1V) {        // 136 builder threads
    int l = tid / K1V, k = tid % K1V;
    int n_ = n0 + l;
    float w0 = 0, w1 = 0, w2 = 0, w3 = 0, dc = 0;
    int idx = 0;
    if (n_ < N) {
      float d = dist[(long)n_ * K1V + k];
      idx = nn[(long)n_ * K1V + k];
      float d2 = d * d;
      w0 = __expf(-d2 * 0.25f);
      w1 = __expf(-d2 * 0.50f);
      w2 = __expf(-d2 * 0.75f);
      w3 = __expf(-d2);
      if (idx == -1) { w0 = w1 = w2 = w3 = 0.0f; }
      if (w0 < 1e-5f) w0 = 0.0f;
      if (w1 < 1e-5f) w1 = 0.0f;
      if (w2 < 1e-5f) w2 = 0.0f;
      if (w3 < 1e-5f) w3 = 0.0f;
      dc = isinf(d) ? 0.0f : d;
      if (idx < 0 || idx >= N) idx = 0;   // its w==0; safe address
    }
    wl[l][k][0] = w0; wl[l][k][1] = w1; wl[l][k][2] = w2; wl[l][k][3] = w3;
    dl[l][k] = dc; nl[l][k] = idx;
  }
  __syncthreads();

  if (tid < 8 * HV) {         // fold dist_agg once per (node, head)
    int l = tid >> 2, h = tid & 3;
    float s = 0.0f;
#pragma unroll
    for (int k = 0; k < K1V; ++k) s = fmaf(wl[l][k][h], dl[l][k], s);
    dagl[l][h] = s;
  }
  __syncthreads();

  int ln = tid >> 5;          // local node
  int c  = tid & 31;          // channel
  int n  = n0 + ln;
  if (n >= N) return;

  const float* base = xp + (size_t)bt * N * COUT + c;
  float a0 = dagl[ln][0], a1 = dagl[ln][1], a2 = dagl[ln][2], a3 = dagl[ln][3];

#pragma unroll
  for (int k = 0; k < K1V; ++k) {
    int   idx = nl[ln][k];
    float v   = base[(size_t)idx * COUT];
    v4f w4 = *(const v4f*)&wl[ln][k][0];
    a0 = fmaf(w4.x, v, a0);
    a1 = fmaf(w4.y, v, a1);
    a2 = fmaf(w4.z, v, a2);
    a3 = fmaf(w4.w, v, a3);
  }

  float* ob = out + (((size_t)bt * N + n) * HV) * COUT + c;
  __builtin_nontemporal_store(a0, ob);
  __builtin_nontemporal_store(a1, ob + COUT);
  __builtin_nontemporal_store(a2, ob + 2 * COUT);
  __builtin_nontemporal_store(a3, ob + 3 * COUT);
}

extern "C" void kernel_launch(void* const* d_in, const int* in_sizes, int n_in,
                              void* d_out, int out_size, void* d_ws, size_t ws_size,
                              hipStream_t stream) {
  const float* x    = (const float*)d_in[0];
  const float* W    = (const float*)d_in[1];
  const float* b    = (const float*)d_in[2];
  const float* dist = (const float*)d_in[3];
  const int*   nn   = (const int*)d_in[4];
  float* out = (float*)d_out;
  float* xp  = (float*)d_ws;   // (BT, N, 32) fp32 = 30.72 MB

  int  N  = in_sizes[4] / K1V;                 // 10000
  long M  = (long)in_sizes[0] / CIN;           // BT * N = 240000
  int  BT = (int)(M / N);                      // 24

  proj_kernel<<<(int)((M + RPB - 1) / RPB), 256, 0, stream>>>(x, W, b, xp, M);

  dim3 grid((N + 7) / 8, BT);                  // 1250 x 24, x fastest
  gcn_kernel<<<grid, 256, 0, stream>>>(xp, dist, nn, out, N);
}